// Round 10
// baseline (246.186 us; speedup 1.0000x reference)
//
#include <hip/hip_runtime.h>
#include <hip/hip_bf16.h>

#define N_NODES 100000
#define NFEAT 256
#define NHID 128
#define NCLASS 8

#define NBLK 1024                      // scat2 edge blocks (+1 wc block)
#define BSH 8                          // bucket = dst >> 8 (256 nodes/bucket)
#define BUCK 256
#define NBUCK ((N_NODES + BUCK - 1) / BUCK)   // 391
#define CAPB 4608                      // fixed region per bucket (mean 4096, sd 64)
#define CHUNK 1564                     // edges per scat2 block (multiple of 4)
#define OVCAP 8192                     // spill capacity (expected usage: 0)

// ---------------------------------------------------------------------------
// K1 scat2: block NBLK precomputes WcT=(W1@Wfc)^T and cvec=b1@Wfc+bfc.
// Blocks 0..NBLK-1: stage CHUNK edges in LDS, LDS-histogram by bucket,
// reserve [base,base+cnt) in the bucket's fixed region via ONE global atomic
// per (block,bucket), then scatter packed (src<<8|local_dst). Excess -> spill.
__global__ __launch_bounds__(256) void scat2_kernel(
        const int* __restrict__ esrc, const int* __restrict__ edst,
        const float* __restrict__ W1, const float* __restrict__ b1,
        const float* __restrict__ Wfc, const float* __restrict__ bfc,
        float* __restrict__ WcT, float* __restrict__ cvec,
        int* __restrict__ cursor, int* __restrict__ ebufP,
        int* __restrict__ ovcnt, int2* __restrict__ ovbuf, int nE) {
    __shared__ int2  ed[CHUNK];
    __shared__ int   hcnt[NBUCK];
    __shared__ int   hbase[NBUCK];
    __shared__ int   hcur[NBUCK];
    __shared__ float wfs[NHID * NCLASS];
    __shared__ float bs[NHID];
    int tid = threadIdx.x;

    if (blockIdx.x == NBLK) {          // Wc / cvec precompute
        for (int i = tid; i < NHID * NCLASS; i += 256) wfs[i] = Wfc[i];
        if (tid < NHID) bs[tid] = b1[tid];
        __syncthreads();
        float acc[NCLASS] = {};
        for (int h = 0; h < NHID; h++) {
            float w = W1[tid * NHID + h];
            #pragma unroll
            for (int c = 0; c < NCLASS; c++) acc[c] += w * wfs[h * NCLASS + c];
        }
        #pragma unroll
        for (int c = 0; c < NCLASS; c++) WcT[c * NFEAT + tid] = acc[c];
        if (tid < NCLASS) {
            float a = bfc[tid];
            for (int h = 0; h < NHID; h++) a += bs[h] * wfs[h * NCLASS + tid];
            cvec[tid] = a;
        }
        return;
    }

    for (int i = tid; i < NBUCK; i += 256) hcnt[i] = 0;
    int e0 = blockIdx.x * CHUNK;
    int e1 = min(e0 + CHUNK, nE);
    int nloc = e1 - e0;
    __syncthreads();

    // stage + per-block histogram
    for (int i = tid * 4; i + 3 < nloc; i += 1024) {
        int4 s = *(const int4*)&esrc[e0 + i];
        int4 d = *(const int4*)&edst[e0 + i];
        ed[i + 0] = make_int2(s.x, d.x);
        ed[i + 1] = make_int2(s.y, d.y);
        ed[i + 2] = make_int2(s.z, d.z);
        ed[i + 3] = make_int2(s.w, d.w);
        atomicAdd(&hcnt[d.x >> BSH], 1);
        atomicAdd(&hcnt[d.y >> BSH], 1);
        atomicAdd(&hcnt[d.z >> BSH], 1);
        atomicAdd(&hcnt[d.w >> BSH], 1);
    }
    int full = nloc & ~3;
    if (full + tid < nloc) {
        int s = esrc[e0 + full + tid], d = edst[e0 + full + tid];
        ed[full + tid] = make_int2(s, d);
        atomicAdd(&hcnt[d >> BSH], 1);
    }
    __syncthreads();

    // one reservation atomic per touched bucket
    for (int i = tid; i < NBUCK; i += 256) {
        int c = hcnt[i];
        hbase[i] = c ? atomicAdd(&cursor[i], c) : 0;
        hcur[i] = 0;
    }
    __syncthreads();

    // scatter from LDS into fixed regions
    for (int i = tid; i < nloc; i += 256) {
        int2 sd = ed[i];
        int b = sd.y >> BSH;
        int r = hbase[b] + atomicAdd(&hcur[b], 1);
        if (r < CAPB) ebufP[b * CAPB + r] = (sd.x << BSH) | (sd.y & (BUCK - 1));
        else { int p = atomicAdd(ovcnt, 1); if (p < OVCAP) ovbuf[p] = sd; }
    }
}

// ---------------------------------------------------------------------------
// K2 degz: fused per-node degree + Z. Block = half-bucket (128 nodes).
// Phase A: count local in-degrees from the bucket region (+spills) via LDS
// atomics -> dinv in LDS. Phase B: Zs[row] = (X[row]@Wc)*dinv, rows 128.
__global__ __launch_bounds__(512) void degz_kernel(
        const float* __restrict__ X, const float* __restrict__ WcT,
        const int* __restrict__ cursor, const int* __restrict__ ebufP,
        const int* __restrict__ ovcnt, const int2* __restrict__ ovbuf,
        float* __restrict__ Zs, int n) {
    __shared__ int    cnt[128];
    __shared__ float  sdinv[128];
    __shared__ float4 wlds[NCLASS * 64];   // 512 float4 = WcT
    int tid  = threadIdx.x;
    int b    = blockIdx.x >> 1;
    int half = blockIdx.x & 1;

    if (tid < 128) cnt[tid] = 0;
    wlds[tid] = ((const float4*)WcT)[tid];
    __syncthreads();

    int n_in = min(cursor[b], CAPB);
    const int* reg = ebufP + b * CAPB;
    for (int e = tid * 4; e + 3 < n_in; e += 2048) {
        int4 p = *(const int4*)&reg[e];
        int l0 = p.x & 255, l1 = p.y & 255, l2 = p.z & 255, l3 = p.w & 255;
        if ((l0 >> 7) == half) atomicAdd(&cnt[l0 & 127], 1);
        if ((l1 >> 7) == half) atomicAdd(&cnt[l1 & 127], 1);
        if ((l2 >> 7) == half) atomicAdd(&cnt[l2 & 127], 1);
        if ((l3 >> 7) == half) atomicAdd(&cnt[l3 & 127], 1);
    }
    int full = n_in & ~3;
    if (full + tid < n_in) {
        int l = reg[full + tid] & 255;
        if ((l >> 7) == half) atomicAdd(&cnt[l & 127], 1);
    }
    int nov = min(*ovcnt, OVCAP);
    for (int i = tid; i < nov; i += 512) {
        int2 sd = ovbuf[i];
        if ((sd.y >> BSH) == b && ((sd.y >> 7) & 1) == half)
            atomicAdd(&cnt[sd.y & 127], 1);
    }
    __syncthreads();
    if (tid < 128) sdinv[tid] = rsqrtf((float)(cnt[tid] + 1));
    __syncthreads();

    // Z phase: 8 waves x 8 rows/pass x 2 passes = 128 rows
    int lane = tid & 63, wave = tid >> 6;
    int sub = lane & 7, rsub = lane >> 3;
    int node_base = (b << BSH) + (half << 7);
    #pragma unroll
    for (int p = 0; p < 2; p++) {
        int rl  = p * 64 + wave * 8 + rsub;
        int row = node_base + rl;
        if (row < n) {
            const float4* xr = (const float4*)(X + (long)row * NFEAT);
            float4 xv[8];
            #pragma unroll
            for (int k = 0; k < 8; k++) xv[k] = xr[sub + 8 * k];
            float res = 0.f;
            #pragma unroll
            for (int c = 0; c < NCLASS; c++) {
                float s = 0.f;
                #pragma unroll
                for (int k = 0; k < 8; k++) {
                    float4 w = wlds[c * 64 + sub + 8 * k];
                    s += xv[k].x * w.x + xv[k].y * w.y + xv[k].z * w.z + xv[k].w * w.w;
                }
                s += __shfl_xor(s, 1);
                s += __shfl_xor(s, 2);
                s += __shfl_xor(s, 4);
                if (sub == c) res = s;
            }
            Zs[(long)row * NCLASS + sub] = res * sdinv[rl];
        }
    }
}

// ---------------------------------------------------------------------------
// K3 sort_gather: in-LDS counting sort of the bucket region + register gather.
__global__ __launch_bounds__(512) void sort_gather_kernel(
        const float* __restrict__ Zs, const int* __restrict__ ebufP,
        const int* __restrict__ cursor, const int* __restrict__ ovcnt,
        const int2* __restrict__ ovbuf, const float* __restrict__ cvec,
        float* __restrict__ out, int n) {
    __shared__ int cnt[BUCK];
    __shared__ int off[BUCK + 1];
    __shared__ int ss[BUCK];
    __shared__ int sorted[CAPB];
    int b = blockIdx.x, tid = threadIdx.x;
    int n_in = min(cursor[b], CAPB);
    const int* reg = ebufP + b * CAPB;
    const float4* Zs4 = (const float4*)Zs;

    if (tid < BUCK) cnt[tid] = 0;
    __syncthreads();
    for (int e = tid * 4; e + 3 < n_in; e += 2048) {
        int4 p = *(const int4*)&reg[e];
        atomicAdd(&cnt[p.x & 255], 1);
        atomicAdd(&cnt[p.y & 255], 1);
        atomicAdd(&cnt[p.z & 255], 1);
        atomicAdd(&cnt[p.w & 255], 1);
    }
    int full = n_in & ~3;
    if (full + tid < n_in) atomicAdd(&cnt[reg[full + tid] & 255], 1);
    __syncthreads();

    int t = (tid < BUCK) ? cnt[tid] : 0;
    if (tid < BUCK) ss[tid] = t;
    __syncthreads();
    for (int o = 1; o < BUCK; o <<= 1) {
        int u = 0;
        if (tid < BUCK && tid >= o) u = ss[tid - o];
        __syncthreads();
        if (tid < BUCK) ss[tid] += u;
        __syncthreads();
    }
    if (tid < BUCK) {
        off[tid] = ss[tid] - t;
        cnt[tid] = ss[tid] - t;         // cursor
        if (tid == BUCK - 1) off[BUCK] = ss[tid];
    }
    __syncthreads();

    for (int e = tid * 4; e + 3 < n_in; e += 2048) {
        int4 p = *(const int4*)&reg[e];
        int s0 = atomicAdd(&cnt[p.x & 255], 1);
        int s1 = atomicAdd(&cnt[p.y & 255], 1);
        int s2 = atomicAdd(&cnt[p.z & 255], 1);
        int s3 = atomicAdd(&cnt[p.w & 255], 1);
        sorted[s0] = p.x >> BSH;
        sorted[s1] = p.y >> BSH;
        sorted[s2] = p.z >> BSH;
        sorted[s3] = p.w >> BSH;
    }
    if (full + tid < n_in) {
        int p = reg[full + tid];
        int slot = atomicAdd(&cnt[p & 255], 1);
        sorted[slot] = p >> BSH;
    }
    __syncthreads();

    int li = tid >> 1;
    int h  = tid & 1;
    int node = (b << BSH) + li;
    if (node < n) {
        int k0 = off[li], k1 = off[li + 1];
        float4 a = Zs4[node * 2 + h];                 // self-loop (pre-scaled)
        int k = k0;
        for (; k + 1 < k1; k += 2) {
            int s0 = sorted[k], s1 = sorted[k + 1];
            float4 z0 = Zs4[s0 * 2 + h];
            float4 z1 = Zs4[s1 * 2 + h];
            a.x += z0.x + z1.x; a.y += z0.y + z1.y;
            a.z += z0.z + z1.z; a.w += z0.w + z1.w;
        }
        if (k < k1) {
            float4 z = Zs4[sorted[k] * 2 + h];
            a.x += z.x; a.y += z.y; a.z += z.z; a.w += z.w;
        }
        int nov = min(*ovcnt, OVCAP);                 // spills (normally 0)
        int m = 0;
        for (int i = 0; i < nov; i++) {
            int2 sd = ovbuf[i];
            if (sd.y == node) {
                float4 z = Zs4[sd.x * 2 + h];
                a.x += z.x; a.y += z.y; a.z += z.z; a.w += z.w;
                m++;
            }
        }
        float dd = rsqrtf((float)(k1 - k0 + m + 1));
        float4 cv = ((const float4*)cvec)[h];
        float4 o;
        o.x = a.x * dd + cv.x; o.y = a.y * dd + cv.y;
        o.z = a.z * dd + cv.z; o.w = a.w * dd + cv.w;
        ((float4*)out)[node * 2 + h] = o;
    }
}

// ---------------------------------------------------------------------------
extern "C" void kernel_launch(void* const* d_in, const int* in_sizes, int n_in,
                              void* d_out, int out_size, void* d_ws, size_t ws_size,
                              hipStream_t stream) {
    const float* x    = (const float*)d_in[0];   // [N, 256]
    const int*   eidx = (const int*)d_in[1];     // [2, E]
    const float* W1   = (const float*)d_in[2];   // [256, 128]
    const float* b1   = (const float*)d_in[3];   // [128]
    const float* Wfc  = (const float*)d_in[4];   // [128, 8]
    const float* bfc  = (const float*)d_in[5];   // [8]
    float* out = (float*)d_out;

    const int N = N_NODES;
    const int E = in_sizes[1] / 2;

    const int* esrc = eidx;
    const int* edst = eidx + E;

    // workspace layout (~10.5 MB); only cursor+ovcnt need zeroing (1568 B).
    float* Zs     = (float*)d_ws;                    // 8N floats (16B aligned)
    float* cvec   = Zs + (long)8 * N;                // 8
    float* WcT    = cvec + 8;                        // 2048
    int*   ebufP  = (int*)(WcT + NCLASS * NFEAT);    // NBUCK*CAPB (16B aligned)
    int*   cursor = ebufP + (long)NBUCK * CAPB;      // NBUCK
    int*   ovcnt  = cursor + NBUCK;                  // 1
    int2*  ovbuf  = (int2*)(ovcnt + 1);              // OVCAP (8B aligned)

    hipMemsetAsync(cursor, 0, (size_t)(NBUCK + 1) * sizeof(int), stream);

    scat2_kernel<<<NBLK + 1, 256, 0, stream>>>(esrc, edst, W1, b1, Wfc, bfc,
                                               WcT, cvec, cursor, ebufP,
                                               ovcnt, ovbuf, E);
    degz_kernel<<<2 * NBUCK, 512, 0, stream>>>(x, WcT, cursor, ebufP,
                                               ovcnt, ovbuf, Zs, N);
    sort_gather_kernel<<<NBUCK, 512, 0, stream>>>(Zs, ebufP, cursor,
                                                  ovcnt, ovbuf, cvec, out, N);
}